// Round 6
// baseline (250.648 us; speedup 1.0000x reference)
//
#include <hip/hip_runtime.h>

// BilinearPooling: out[i,k] = mean_j(conv1[i,j]) * conv2[i,k]
// B=256, J=K=14*14*256=50176. 154 MB logical traffic, ~24.5 us copy-rate floor.
//
// Round-6: single-dispatch producer-consumer. All prior structures (serial
// 2-phase, split 2-dispatch, fused+pins) tie at ~43-46 us (~3.5 TB/s) because
// the out-write stream never overlaps the read streams chip-wide. Here:
//   - 1792 blocks x 256 thr (7 blocks/row, 7/CU, ALL co-resident:
//     1792 thr/CU <= 2048, VGPR<=64 via launch_bounds(256,8), LDS 24 B).
//   - Each block: issue 7 conv2 prefetch loads, reduce its conv1 segment,
//     atomicAdd partial sum + release-increment done[row] in d_ws,
//     tid0 spins (s_sleep) until done[row]==7, then scale staged regs + NT store.
//   - Rows finish in a staggered wavefront -> reads and writes concurrently in
//     flight; no dispatch drain bubble; no block-wide serialization of streams.
// Deadlock-safe: every block completes its reduce before spinning, and the
// whole grid is co-resident by capacity (448K of 524K max threads).

typedef float f32x4 __attribute__((ext_vector_type(4)));

#define ROW_ELEMS 50176
#define ROW_VEC   12544          // float4 per row
#define BPR       7              // blocks per row
#define SEG_VEC   1792           // ROW_VEC / BPR
#define THREADS   256
#define ITERS     7              // SEG_VEC / THREADS (exact, no tail)

__global__ __launch_bounds__(THREADS, 8)
void bp_onepass_kernel(const f32x4* __restrict__ c1,
                       const f32x4* __restrict__ c2,
                       f32x4* __restrict__ out,
                       float* __restrict__ rowsum,
                       int*   __restrict__ done) {
    const int b   = blockIdx.x;
    const int row = b / BPR;
    const int seg = b % BPR;
    const int tid = threadIdx.x;
    const size_t base = (size_t)row * ROW_VEC + (size_t)seg * SEG_VEC + tid;

    const f32x4* __restrict__ p1 = c1 + base;
    const f32x4* __restrict__ p2 = c2 + base;

    // conv2 prefetch issued FIRST (oldest in the VMEM queue)...
    f32x4 st0 = p2[0 * THREADS];
    f32x4 st1 = p2[1 * THREADS];
    f32x4 st2 = p2[2 * THREADS];
    f32x4 st3 = p2[3 * THREADS];
    f32x4 st4 = p2[4 * THREADS];
    f32x4 st5 = p2[5 * THREADS];
    f32x4 st6 = p2[6 * THREADS];

    // ...then the conv1 reduction stream.
    float s = 0.0f;
    #pragma unroll
    for (int i = 0; i < ITERS; ++i) {
        f32x4 v = p1[i * THREADS];
        s += (v[0] + v[1]) + (v[2] + v[3]);
    }

    // Single combined pin: keeps all 7 staged values live in VGPRs here
    // (one asm, so it cannot be split/hoisted per-value like round-5's).
    asm volatile("" : "+v"(st0), "+v"(st1), "+v"(st2), "+v"(st3),
                      "+v"(st4), "+v"(st5), "+v"(st6));

    // Wave-64 butterfly + 4-wave LDS combine.
    #pragma unroll
    for (int off = 32; off > 0; off >>= 1)
        s += __shfl_down(s, off, 64);

    __shared__ float wsum[THREADS / 64];
    __shared__ float mean_s;
    const int lane = tid & 63;
    const int wid  = tid >> 6;
    if (lane == 0) wsum[wid] = s;
    __syncthreads();

    if (tid == 0) {
        const float bsum = (wsum[0] + wsum[1]) + (wsum[2] + wsum[3]);
        __hip_atomic_fetch_add(&rowsum[row], bsum,
                               __ATOMIC_RELAXED, __HIP_MEMORY_SCOPE_AGENT);
        __hip_atomic_fetch_add(&done[row], 1,
                               __ATOMIC_RELEASE, __HIP_MEMORY_SCOPE_AGENT);
        // Producer-consumer: wait for this row's 7 partials.
        while (__hip_atomic_load(&done[row],
                                 __ATOMIC_ACQUIRE, __HIP_MEMORY_SCOPE_AGENT) < BPR)
            __builtin_amdgcn_s_sleep(2);
        mean_s = __hip_atomic_load(&rowsum[row],
                                   __ATOMIC_RELAXED, __HIP_MEMORY_SCOPE_AGENT)
                 * (1.0f / (float)ROW_ELEMS);
    }
    __syncthreads();
    const float m = mean_s;

    f32x4* __restrict__ po = out + base;
    st0 *= m; __builtin_nontemporal_store(st0, &po[0 * THREADS]);
    st1 *= m; __builtin_nontemporal_store(st1, &po[1 * THREADS]);
    st2 *= m; __builtin_nontemporal_store(st2, &po[2 * THREADS]);
    st3 *= m; __builtin_nontemporal_store(st3, &po[3 * THREADS]);
    st4 *= m; __builtin_nontemporal_store(st4, &po[4 * THREADS]);
    st5 *= m; __builtin_nontemporal_store(st5, &po[5 * THREADS]);
    st6 *= m; __builtin_nontemporal_store(st6, &po[6 * THREADS]);
}

extern "C" void kernel_launch(void* const* d_in, const int* in_sizes, int n_in,
                              void* d_out, int out_size, void* d_ws, size_t ws_size,
                              hipStream_t stream) {
    const f32x4* c1 = (const f32x4*)d_in[0];
    const f32x4* c2 = (const f32x4*)d_in[1];
    f32x4* out = (f32x4*)d_out;

    // d_ws layout: [0,1KB) rowsum (256 floats), [1KB,2KB) done (256 ints).
    float* rowsum = (float*)d_ws;
    int*   done   = (int*)((char*)d_ws + 1024);
    hipMemsetAsync(d_ws, 0, 2048, stream);   // stream-ordered, graph-capturable

    bp_onepass_kernel<<<256 * BPR, THREADS, 0, stream>>>(c1, c2, out, rowsum, done);
}

// Round 8
// 161.681 us; speedup vs baseline: 1.5503x; 1.5503x over previous
//
#include <hip/hip_runtime.h>

// BilinearPooling: out[i,k] = mean_j(conv1[i,j]) * conv2[i,k]
// B=256, J=K=14*14*256=50176. 154 MB logical traffic, ~24.5 us copy-rate floor.
//
// Round-8 (= round-7 resubmit; container failed, kernel never ran):
// fill-granularity streaming. Four prior structures tie at ~43 us (~2.4 TB/s)
// while the harness fill kernel hits 6.6 TB/s in the same capture window using
// tiny 256-thr blocks / huge grid / ~1 vector op per thread. Match that shape
// exactly (ROW_VEC = 12544 = 49*256 -> 49 blocks/row, one float4 per thread,
// no per-thread loops, blocks retire independently):
//   1) bp_reduce: 12544 blk x 256 thr, 1 NT float4 load, wave+LDS reduce,
//      one device-scope atomicAdd(mean-scaled partial) per block.
//   2) bp_scale:  12544 blk x 256 thr, s_load mean, 1 float4 load, NT store.
// No cross-block spin (R6's agent-scope acquire polling invalidated L2s and
// collapsed BW to 680 GB/s - reverted).

typedef float f32x4 __attribute__((ext_vector_type(4)));

#define ROW_ELEMS 50176
#define ROW_VEC   12544u          // float4 per row = 49 * 256
#define BPR       49u             // blocks per row
#define THREADS   256
#define GRID      (256u * BPR)    // 12544 blocks

__global__ __launch_bounds__(THREADS)
void bp_reduce(const f32x4* __restrict__ c1, float* __restrict__ rowsum) {
    const unsigned bid = blockIdx.x;
    const unsigned row = bid / BPR;                       // magic-mul
    const unsigned off = (bid - row * BPR) * THREADS + threadIdx.x;
    const size_t idx = (size_t)row * ROW_VEC + off;

    // conv1 is consumed once; NT load keeps L2 clean.
    f32x4 v = __builtin_nontemporal_load(&c1[idx]);
    float s = (v[0] + v[1]) + (v[2] + v[3]);

    // wave-64 butterfly
    #pragma unroll
    for (int o = 32; o > 0; o >>= 1)
        s += __shfl_down(s, o, 64);

    __shared__ float wsum[THREADS / 64];
    const int lane = threadIdx.x & 63;
    const int wid  = threadIdx.x >> 6;
    if (lane == 0) wsum[wid] = s;
    __syncthreads();
    if (threadIdx.x == 0) {
        const float t = (wsum[0] + wsum[1]) + (wsum[2] + wsum[3]);
        // device-scope by default; pre-scaled so rowsum accumulates the mean.
        atomicAdd(&rowsum[row], t * (1.0f / (float)ROW_ELEMS));
    }
}

__global__ __launch_bounds__(THREADS)
void bp_scale(const f32x4* __restrict__ c2,
              const float* __restrict__ rowsum,
              f32x4* __restrict__ out) {
    const unsigned bid = blockIdx.x;
    const unsigned row = bid / BPR;                       // magic-mul
    const unsigned off = (bid - row * BPR) * THREADS + threadIdx.x;
    const size_t idx = (size_t)row * ROW_VEC + off;

    const float m = rowsum[row];     // block-uniform -> scalar load, L2-hot
    f32x4 v = c2[idx];
    v *= m;
    __builtin_nontemporal_store(v, &out[idx]);
}

extern "C" void kernel_launch(void* const* d_in, const int* in_sizes, int n_in,
                              void* d_out, int out_size, void* d_ws, size_t ws_size,
                              hipStream_t stream) {
    const f32x4* c1 = (const f32x4*)d_in[0];
    const f32x4* c2 = (const f32x4*)d_in[1];
    f32x4* out = (f32x4*)d_out;
    float* rowsum = (float*)d_ws;    // 256 floats = 1 KB

    hipMemsetAsync(d_ws, 0, 256 * sizeof(float), stream);  // capture-safe (R6)
    bp_reduce<<<GRID, THREADS, 0, stream>>>(c1, rowsum);
    bp_scale <<<GRID, THREADS, 0, stream>>>(c2, rowsum, out);
}

// Round 9
// 138.797 us; speedup vs baseline: 1.8059x; 1.1649x over previous
//
#include <hip/hip_runtime.h>

// BilinearPooling: out[i,k] = mean_j(conv1[i,j]) * conv2[i,k]
// B=256, J=K=14*14*256=50176. 154 MB logical traffic, ~24.5 us copy-rate floor.
//
// Round-9: composed from the two best MEASURED phases.
//   - R8 post-mortem: 1-float4/thread scale = 4.3 TB/s (fastest phase yet);
//     but 1-float4/thread reduce = 1.2 TB/s (latency-starved blocks + 12544
//     device fp32 atomicAdds into 16 cachelines serializing at coherence pt).
//   - Fix: reduce uses 7 float4/thread (R1 geometry, MLP-rich) and ONE plain
//     store per block to a DISTINCT partials[blockIdx.x] (no atomics, no
//     memset — all 1792 entries written unconditionally).
//   - Scale keeps R8's shape: 12544 blk x 256 thr, 1 float4/thread, block-
//     uniform scalar partial loads (7 floats, L2-hot), NT store.

typedef float f32x4 __attribute__((ext_vector_type(4)));

#define ROW_ELEMS 50176
#define ROW_VEC   12544u          // float4 per row
#define THREADS   256

// reduce geometry: 7 blocks/row, 7 float4/thread
#define R_BPR     7u
#define R_SEG     1792u           // ROW_VEC / R_BPR
#define R_ITERS   7               // R_SEG / THREADS
#define R_GRID    (256u * R_BPR)  // 1792 blocks

// scale geometry: 49 blocks/row, 1 float4/thread
#define S_BPR     49u
#define S_GRID    (256u * S_BPR)  // 12544 blocks

__global__ __launch_bounds__(THREADS)
void bp_reduce(const f32x4* __restrict__ c1, float* __restrict__ partials) {
    const unsigned bid = blockIdx.x;
    const unsigned row = bid / R_BPR;                    // magic-mul
    const unsigned seg = bid - row * R_BPR;
    const f32x4* __restrict__ p =
        c1 + (size_t)row * ROW_VEC + (size_t)seg * R_SEG + threadIdx.x;

    // 7 independent float4 loads in flight per lane before the adds need them.
    float s = 0.0f;
    #pragma unroll
    for (int i = 0; i < R_ITERS; ++i) {
        f32x4 v = p[i * THREADS];
        s += (v[0] + v[1]) + (v[2] + v[3]);
    }

    // wave-64 butterfly + 4-wave LDS combine
    #pragma unroll
    for (int o = 32; o > 0; o >>= 1)
        s += __shfl_down(s, o, 64);

    __shared__ float wsum[THREADS / 64];
    const int lane = threadIdx.x & 63;
    const int wid  = threadIdx.x >> 6;
    if (lane == 0) wsum[wid] = s;
    __syncthreads();
    if (threadIdx.x == 0) {
        // plain store, distinct address per block: no atomic serialization.
        partials[bid] = (wsum[0] + wsum[1]) + (wsum[2] + wsum[3]);
    }
}

__global__ __launch_bounds__(THREADS)
void bp_scale(const f32x4* __restrict__ c2,
              const float* __restrict__ partials,
              f32x4* __restrict__ out) {
    const unsigned bid = blockIdx.x;
    const unsigned row = bid / S_BPR;                    // magic-mul
    const unsigned off = (bid - row * S_BPR) * THREADS + threadIdx.x;
    const size_t idx = (size_t)row * ROW_VEC + off;

    // 28 B of partials per row, block-uniform -> scalar loads, L2-hot
    // (written by bp_reduce; inter-dispatch ordering guarantees visibility).
    const float* pr = partials + row * R_BPR;
    const float t = ((pr[0] + pr[1]) + (pr[2] + pr[3]))
                  + ((pr[4] + pr[5]) + pr[6]);
    const float m = t * (1.0f / (float)ROW_ELEMS);

    f32x4 v = c2[idx];
    v *= m;
    __builtin_nontemporal_store(v, &out[idx]);
}

extern "C" void kernel_launch(void* const* d_in, const int* in_sizes, int n_in,
                              void* d_out, int out_size, void* d_ws, size_t ws_size,
                              hipStream_t stream) {
    const f32x4* c1 = (const f32x4*)d_in[0];
    const f32x4* c2 = (const f32x4*)d_in[1];
    f32x4* out = (f32x4*)d_out;
    float* partials = (float*)d_ws;   // 1792 floats = 7 KB, fully overwritten

    bp_reduce<<<R_GRID, THREADS, 0, stream>>>(c1, partials);
    bp_scale <<<S_GRID, THREADS, 0, stream>>>(c2, partials, out);
}

// Round 11
// 135.688 us; speedup vs baseline: 1.8472x; 1.0229x over previous
//
#include <hip/hip_runtime.h>

// BilinearPooling: out[i,k] = mean_j(conv1[i,j]) * conv2[i,k]
// B=256, J=K=14*14*256=50176. 154 MB logical traffic.
//
// Round-11 (= round-10 resubmit; broker timed out, kernel never ran):
// single-variable A/B vs round-9 — NT loads.
// Unified model from R0-R9: every structure ties at ~44 us because the READ
// path runs at ~2.35 TB/s in all of them (reduce: 51.4MB/21.5us; scale read
// component: 51.4MB/23us; fused: 2 serialized read phases = 43us). Writes are
// free/overlapped (fill = 6.6 TB/s). Hypothesis: read cap = cache-allocation
// overhead (harness re-poison flushes L3 each iter, so allocating 100 MB of
// streamed-once lines into L2/L3 is pure overhead). NT loads bypass allocate.
// ONLY change vs R9: __builtin_nontemporal_load on c1 and c2.
//   null result (+-2us) => read-path roofline established (6 structures x
//   both cache modes all at 103 MB / 2.35 TB/s).

typedef float f32x4 __attribute__((ext_vector_type(4)));

#define ROW_ELEMS 50176
#define ROW_VEC   12544u          // float4 per row
#define THREADS   256

// reduce geometry: 7 blocks/row, 7 float4/thread
#define R_BPR     7u
#define R_SEG     1792u           // ROW_VEC / R_BPR
#define R_ITERS   7               // R_SEG / THREADS
#define R_GRID    (256u * R_BPR)  // 1792 blocks

// scale geometry: 49 blocks/row, 1 float4/thread
#define S_BPR     49u
#define S_GRID    (256u * S_BPR)  // 12544 blocks

__global__ __launch_bounds__(THREADS)
void bp_reduce(const f32x4* __restrict__ c1, float* __restrict__ partials) {
    const unsigned bid = blockIdx.x;
    const unsigned row = bid / R_BPR;                    // magic-mul
    const unsigned seg = bid - row * R_BPR;
    const f32x4* __restrict__ p =
        c1 + (size_t)row * ROW_VEC + (size_t)seg * R_SEG + threadIdx.x;

    // 7 independent NT float4 loads in flight per lane (streamed once;
    // bypass L2/L3 allocation).
    float s = 0.0f;
    #pragma unroll
    for (int i = 0; i < R_ITERS; ++i) {
        f32x4 v = __builtin_nontemporal_load(&p[i * THREADS]);
        s += (v[0] + v[1]) + (v[2] + v[3]);
    }

    // wave-64 butterfly + 4-wave LDS combine
    #pragma unroll
    for (int o = 32; o > 0; o >>= 1)
        s += __shfl_down(s, o, 64);

    __shared__ float wsum[THREADS / 64];
    const int lane = threadIdx.x & 63;
    const int wid  = threadIdx.x >> 6;
    if (lane == 0) wsum[wid] = s;
    __syncthreads();
    if (threadIdx.x == 0) {
        // plain store, distinct address per block: no atomic serialization.
        partials[bid] = (wsum[0] + wsum[1]) + (wsum[2] + wsum[3]);
    }
}

__global__ __launch_bounds__(THREADS)
void bp_scale(const f32x4* __restrict__ c2,
              const float* __restrict__ partials,
              f32x4* __restrict__ out) {
    const unsigned bid = blockIdx.x;
    const unsigned row = bid / S_BPR;                    // magic-mul
    const unsigned off = (bid - row * S_BPR) * THREADS + threadIdx.x;
    const size_t idx = (size_t)row * ROW_VEC + off;

    // 28 B of partials per row, block-uniform -> scalar loads, L2-hot
    // (written by bp_reduce; inter-dispatch ordering guarantees visibility).
    const float* pr = partials + row * R_BPR;
    const float t = ((pr[0] + pr[1]) + (pr[2] + pr[3]))
                  + ((pr[4] + pr[5]) + pr[6]);
    const float m = t * (1.0f / (float)ROW_ELEMS);

    f32x4 v = __builtin_nontemporal_load(&c2[idx]);
    v *= m;
    __builtin_nontemporal_store(v, &out[idx]);
}

extern "C" void kernel_launch(void* const* d_in, const int* in_sizes, int n_in,
                              void* d_out, int out_size, void* d_ws, size_t ws_size,
                              hipStream_t stream) {
    const f32x4* c1 = (const f32x4*)d_in[0];
    const f32x4* c2 = (const f32x4*)d_in[1];
    f32x4* out = (f32x4*)d_out;
    float* partials = (float*)d_ws;   // 1792 floats = 7 KB, fully overwritten

    bp_reduce<<<R_GRID, THREADS, 0, stream>>>(c1, partials);
    bp_scale <<<S_GRID, THREADS, 0, stream>>>(c2, partials, out);
}